// Round 1
// baseline (1848.616 us; speedup 1.0000x reference)
//
#include <hip/hip_runtime.h>

#define HW 65536
#define NBATCH 16
#define CCH 64
#define QKC 32

// workspace layout (float offsets)
#define OFF_WQT 0        // [64][32]  WqT folded
#define OFF_BQ  2048     // [32]
#define OFF_WKT 2080     // [64][32]
#define OFF_BK  4128     // [32]
#define OFF_WVT 4160     // [64][64]
#define OFF_BV  8256     // [64]
#define OFF_WO  8320     // [64][64]  row-major [c][j]
#define OFF_BO  12416    // [64]
#define OFF_F   12544    // [16][32][64]
#define OFF_MT  45312    // [16][32][64]  MT[n][i][c] = sum_j Wo'[c][j]*F[n][i][j]

#define BPN_A 64
#define BPN_B 64

__global__ __launch_bounds__(256) void k0_fold(
    const float* __restrict__ Wq, const float* __restrict__ bq,
    const float* __restrict__ qg, const float* __restrict__ qb,
    const float* __restrict__ qm, const float* __restrict__ qv,
    const float* __restrict__ Wk, const float* __restrict__ bk,
    const float* __restrict__ kg, const float* __restrict__ kb,
    const float* __restrict__ km, const float* __restrict__ kvar,
    const float* __restrict__ Wv, const float* __restrict__ bv,
    const float* __restrict__ vg, const float* __restrict__ vb,
    const float* __restrict__ vm, const float* __restrict__ vvar,
    const float* __restrict__ Wo, const float* __restrict__ bo,
    const float* __restrict__ og, const float* __restrict__ ob,
    const float* __restrict__ om, const float* __restrict__ ovar,
    float* __restrict__ ws)
{
    const int idx = blockIdx.x * 256 + threadIdx.x;
    if (idx < 2048) {                       // WqT[c][i]
        const int c = idx >> 5, i = idx & 31;
        const float s = qg[i] * rsqrtf(qv[i] + 1e-5f);
        ws[OFF_WQT + idx] = Wq[i * 64 + c] * s;
    } else if (idx < 2080) {
        const int i = idx - 2048;
        const float s = qg[i] * rsqrtf(qv[i] + 1e-5f);
        ws[OFF_BQ + i] = bq[i] * s + qb[i] - qm[i] * s;
    } else if (idx < 4128) {                // WkT[c][i]
        const int t = idx - 2080;
        const int c = t >> 5, i = t & 31;
        const float s = kg[i] * rsqrtf(kvar[i] + 1e-5f);
        ws[OFF_WKT + t] = Wk[i * 64 + c] * s;
    } else if (idx < 4160) {
        const int i = idx - 4128;
        const float s = kg[i] * rsqrtf(kvar[i] + 1e-5f);
        ws[OFF_BK + i] = bk[i] * s + kb[i] - km[i] * s;
    } else if (idx < 8256) {                // WvT[c][o]
        const int t = idx - 4160;
        const int c = t >> 6, o = t & 63;
        const float s = vg[o] * rsqrtf(vvar[o] + 1e-5f);
        ws[OFF_WVT + t] = Wv[o * 64 + c] * s;
    } else if (idx < 8320) {
        const int o = idx - 8256;
        const float s = vg[o] * rsqrtf(vvar[o] + 1e-5f);
        ws[OFF_BV + o] = bv[o] * s + vb[o] - vm[o] * s;
    } else if (idx < 12416) {               // Wo'[c][j]
        const int t = idx - 8320;
        const int c = t >> 6, j = t & 63;
        const float s = og[c] * rsqrtf(ovar[c] + 1e-5f);
        ws[OFF_WO + t] = Wo[c * 64 + j] * s;
    } else if (idx < 12480) {
        const int c = idx - 12416;
        const float s = og[c] * rsqrtf(ovar[c] + 1e-5f);
        ws[OFF_BO + c] = bo[c] * s + ob[c] - om[c] * s;
    } else if (idx < 12480 + 32768) {       // zero F (must happen every launch)
        ws[OFF_F + (idx - 12480)] = 0.0f;
    }
}

// Pass A: per pixel compute k (normalized) and v (relu), stage in LDS,
// register-tiled outer-product accumulation of f[n][32][64].
__global__ __launch_bounds__(128, 2) void k1_passA(const float* __restrict__ x,
                                                   const float* __restrict__ wsc,
                                                   float* __restrict__ f)
{
    __shared__ float wkt[2048];
    __shared__ float bks[32];
    __shared__ float wvt[4096];
    __shared__ float bvs[64];
    __shared__ float Kl[128 * 36];   // row stride 36 floats (144B, 16B aligned)
    __shared__ float Vl[128 * 68];   // row stride 68 floats (272B, 16B aligned)

    const int tid = threadIdx.x;
    const int n = blockIdx.x / BPN_A;
    const int bslot = blockIdx.x % BPN_A;

    for (int i = tid; i < 2048; i += 128) wkt[i] = wsc[OFF_WKT + i];
    for (int i = tid; i < 4096; i += 128) wvt[i] = wsc[OFF_WVT + i];
    if (tid < 32) bks[tid] = wsc[OFF_BK + tid];
    if (tid < 64) bvs[tid] = wsc[OFF_BV + tid];
    __syncthreads();

    const int i0 = (tid & 7) * 4;        // 8 i-groups
    const int j0 = (tid >> 3) * 4;       // 16 j-groups
    float facc[4][4];
#pragma unroll
    for (int a = 0; a < 4; a++)
#pragma unroll
        for (int b = 0; b < 4; b++) facc[a][b] = 0.0f;

    const float* xn = x + (size_t)n * CCH * HW;

    for (int chunk = bslot; chunk < HW / 128; chunk += BPN_A) {
        const int s = chunk * 128 + tid;
        float kk[32], vv[64];
#pragma unroll
        for (int i = 0; i < 32; i++) kk[i] = bks[i];
#pragma unroll
        for (int o = 0; o < 64; o++) vv[o] = bvs[o];

#pragma unroll 4
        for (int c = 0; c < 64; c++) {
            const float xc = xn[(size_t)c * HW + s];
#pragma unroll
            for (int i4 = 0; i4 < 8; i4++) {
                const float4 w = *(const float4*)&wkt[c * 32 + i4 * 4];
                kk[i4 * 4 + 0] += w.x * xc;
                kk[i4 * 4 + 1] += w.y * xc;
                kk[i4 * 4 + 2] += w.z * xc;
                kk[i4 * 4 + 3] += w.w * xc;
            }
#pragma unroll
            for (int o4 = 0; o4 < 16; o4++) {
                const float4 w = *(const float4*)&wvt[c * 64 + o4 * 4];
                vv[o4 * 4 + 0] += w.x * xc;
                vv[o4 * 4 + 1] += w.y * xc;
                vv[o4 * 4 + 2] += w.z * xc;
                vv[o4 * 4 + 3] += w.w * xc;
            }
        }

        float ssum = 0.0f;
#pragma unroll
        for (int i = 0; i < 32; i++) ssum += kk[i] * kk[i];
        const float inv = 1.0f / fmaxf(sqrtf(ssum), 1e-12f);

#pragma unroll
        for (int i4 = 0; i4 < 8; i4++) {
            float4 w;
            w.x = kk[i4 * 4 + 0] * inv;
            w.y = kk[i4 * 4 + 1] * inv;
            w.z = kk[i4 * 4 + 2] * inv;
            w.w = kk[i4 * 4 + 3] * inv;
            *(float4*)&Kl[tid * 36 + i4 * 4] = w;
        }
#pragma unroll
        for (int o4 = 0; o4 < 16; o4++) {
            float4 w;
            w.x = fmaxf(vv[o4 * 4 + 0], 0.0f);
            w.y = fmaxf(vv[o4 * 4 + 1], 0.0f);
            w.z = fmaxf(vv[o4 * 4 + 2], 0.0f);
            w.w = fmaxf(vv[o4 * 4 + 3], 0.0f);
            *(float4*)&Vl[tid * 68 + o4 * 4] = w;
        }
        __syncthreads();

        for (int s2 = 0; s2 < 128; s2++) {
            const float4 k4 = *(const float4*)&Kl[s2 * 36 + i0];
            const float4 v4 = *(const float4*)&Vl[s2 * 68 + j0];
            const float ka[4] = {k4.x, k4.y, k4.z, k4.w};
            const float va[4] = {v4.x, v4.y, v4.z, v4.w};
#pragma unroll
            for (int a = 0; a < 4; a++)
#pragma unroll
                for (int b = 0; b < 4; b++) facc[a][b] += ka[a] * va[b];
        }
        __syncthreads();
    }

    float* fn = f + n * (QKC * CCH);
#pragma unroll
    for (int a = 0; a < 4; a++)
#pragma unroll
        for (int b = 0; b < 4; b++)
            atomicAdd(&fn[(i0 + a) * 64 + (j0 + b)], facc[a][b]);
}

// MT[n][i][c] = sum_j Wo'[c][j] * F[n][i][j]
__global__ __launch_bounds__(256) void k2_M(const float* __restrict__ wsc,
                                            float* __restrict__ ws)
{
    const int idx = blockIdx.x * 256 + threadIdx.x;
    if (idx >= NBATCH * QKC * CCH) return;
    const int n = idx / (QKC * CCH);
    const int r = idx % (QKC * CCH);
    const int i = r >> 6, c = r & 63;
    const float* wo = wsc + OFF_WO + c * 64;
    const float* fr = wsc + OFF_F + n * 2048 + i * 64;
    float acc = 0.0f;
#pragma unroll
    for (int j = 0; j < 64; j++) acc += wo[j] * fr[j];
    ws[OFF_MT + idx] = acc;
}

// Pass B: recompute q and v0 from x; out = relu(bo' + MT^T q) + v0
__global__ __launch_bounds__(256, 2) void k3_passB(const float* __restrict__ x,
                                                   const float* __restrict__ wsc,
                                                   float* __restrict__ out)
{
    __shared__ float wqt[2048];
    __shared__ float bqs[32];
    __shared__ float wvt[4096];
    __shared__ float bvs[64];
    __shared__ float mts[2048];
    __shared__ float bos[64];

    const int tid = threadIdx.x;
    const int n = blockIdx.x / BPN_B;
    const int slot = blockIdx.x % BPN_B;

    for (int i = tid; i < 2048; i += 256) wqt[i] = wsc[OFF_WQT + i];
    for (int i = tid; i < 4096; i += 256) wvt[i] = wsc[OFF_WVT + i];
    for (int i = tid; i < 2048; i += 256) mts[i] = wsc[OFF_MT + n * 2048 + i];
    if (tid < 32) bqs[tid] = wsc[OFF_BQ + tid];
    if (tid < 64) {
        bvs[tid] = wsc[OFF_BV + tid];
        bos[tid] = wsc[OFF_BO + tid];
    }
    __syncthreads();

    const float* xn = x + (size_t)n * CCH * HW;
    float* on = out + (size_t)n * CCH * HW;

    for (int it = 0; it < HW / (BPN_B * 256); it++) {
        const int s = slot * (HW / BPN_B) + it * 256 + tid;

        float xr[64];
#pragma unroll 8
        for (int c = 0; c < 64; c++) xr[c] = xn[(size_t)c * HW + s];

        // q = WqT^T x + bq'
        float q[32];
#pragma unroll
        for (int i = 0; i < 32; i++) q[i] = bqs[i];
#pragma unroll 4
        for (int c = 0; c < 64; c++) {
            const float xc = xr[c];
#pragma unroll
            for (int i4 = 0; i4 < 8; i4++) {
                const float4 w = *(const float4*)&wqt[c * 32 + i4 * 4];
                q[i4 * 4 + 0] += w.x * xc;
                q[i4 * 4 + 1] += w.y * xc;
                q[i4 * 4 + 2] += w.z * xc;
                q[i4 * 4 + 3] += w.w * xc;
            }
        }
        float ssum = 0.0f;
#pragma unroll
        for (int i = 0; i < 32; i++) ssum += q[i] * q[i];
        const float inv = 1.0f / fmaxf(sqrtf(ssum), 1e-12f);
#pragma unroll
        for (int i = 0; i < 32; i++) q[i] *= inv;

        // v0 = WvT^T x + bv'   (xr dies after this)
        float v0[64];
#pragma unroll
        for (int o = 0; o < 64; o++) v0[o] = bvs[o];
#pragma unroll 4
        for (int c = 0; c < 64; c++) {
            const float xc = xr[c];
#pragma unroll
            for (int o4 = 0; o4 < 16; o4++) {
                const float4 w = *(const float4*)&wvt[c * 64 + o4 * 4];
                v0[o4 * 4 + 0] += w.x * xc;
                v0[o4 * 4 + 1] += w.y * xc;
                v0[o4 * 4 + 2] += w.z * xc;
                v0[o4 * 4 + 3] += w.w * xc;
            }
        }

        // o = bo' + MT^T q
        float oo[64];
#pragma unroll
        for (int c = 0; c < 64; c++) oo[c] = bos[c];
#pragma unroll 4
        for (int i = 0; i < 32; i++) {
            const float qi = q[i];
#pragma unroll
            for (int c4 = 0; c4 < 16; c4++) {
                const float4 m = *(const float4*)&mts[i * 64 + c4 * 4];
                oo[c4 * 4 + 0] += m.x * qi;
                oo[c4 * 4 + 1] += m.y * qi;
                oo[c4 * 4 + 2] += m.z * qi;
                oo[c4 * 4 + 3] += m.w * qi;
            }
        }

#pragma unroll 8
        for (int c = 0; c < 64; c++)
            on[(size_t)c * HW + s] = fmaxf(oo[c], 0.0f) + v0[c];
    }
}

extern "C" void kernel_launch(void* const* d_in, const int* in_sizes, int n_in,
                              void* d_out, int out_size, void* d_ws, size_t ws_size,
                              hipStream_t stream)
{
    const float* x    = (const float*)d_in[0];
    const float* Wq   = (const float*)d_in[1];
    const float* bq   = (const float*)d_in[2];
    const float* qg   = (const float*)d_in[3];
    const float* qb   = (const float*)d_in[4];
    const float* qm   = (const float*)d_in[5];
    const float* qv   = (const float*)d_in[6];
    const float* Wk   = (const float*)d_in[7];
    const float* bk   = (const float*)d_in[8];
    const float* kg   = (const float*)d_in[9];
    const float* kb   = (const float*)d_in[10];
    const float* km   = (const float*)d_in[11];
    const float* kvar = (const float*)d_in[12];
    const float* Wv   = (const float*)d_in[13];
    const float* bv   = (const float*)d_in[14];
    const float* vg   = (const float*)d_in[15];
    const float* vb   = (const float*)d_in[16];
    const float* vm   = (const float*)d_in[17];
    const float* vvar = (const float*)d_in[18];
    const float* Wo   = (const float*)d_in[19];
    const float* bo   = (const float*)d_in[20];
    const float* og   = (const float*)d_in[21];
    const float* ob   = (const float*)d_in[22];
    const float* om   = (const float*)d_in[23];
    const float* ovar = (const float*)d_in[24];

    float* ws  = (float*)d_ws;
    float* out = (float*)d_out;

    k0_fold<<<177, 256, 0, stream>>>(Wq, bq, qg, qb, qm, qv,
                                     Wk, bk, kg, kb, km, kvar,
                                     Wv, bv, vg, vb, vm, vvar,
                                     Wo, bo, og, ob, om, ovar, ws);

    k1_passA<<<NBATCH * BPN_A, 128, 0, stream>>>(x, (const float*)ws, ws + OFF_F);

    k2_M<<<128, 256, 0, stream>>>((const float*)ws, ws);

    k3_passB<<<NBATCH * BPN_B, 256, 0, stream>>>(x, (const float*)ws, out);
}

// Round 2
// 610.437 us; speedup vs baseline: 3.0283x; 3.0283x over previous
//
#include <hip/hip_runtime.h>

#define HW 65536
#define NBATCH 16
#define CCH 64
#define QKC 32

// workspace layout (float offsets)
#define OFF_WQT 0        // [64][32]  WqT folded (c-major rows of 32)
#define OFF_BQ  2048     // [32]
#define OFF_WKT 2080     // [64][32]
#define OFF_BK  4128     // [32]
#define OFF_WVT 4160     // [64][64]
#define OFF_BV  8256     // [64]
#define OFF_WO  8320     // [64][64]  row-major [c][j]
#define OFF_BO  12416    // [64]
#define OFF_F   12544    // [16][32][64]
#define OFF_MT  45312    // [16][32][64]  MT[n][i][c] = sum_j Wo'[c][j]*F[n][i][j]

#define BPN_A 64
#define BPN_B 64

__global__ __launch_bounds__(256) void k0_fold(
    const float* __restrict__ Wq, const float* __restrict__ bq,
    const float* __restrict__ qg, const float* __restrict__ qb,
    const float* __restrict__ qm, const float* __restrict__ qv,
    const float* __restrict__ Wk, const float* __restrict__ bk,
    const float* __restrict__ kg, const float* __restrict__ kb,
    const float* __restrict__ km, const float* __restrict__ kvar,
    const float* __restrict__ Wv, const float* __restrict__ bv,
    const float* __restrict__ vg, const float* __restrict__ vb,
    const float* __restrict__ vm, const float* __restrict__ vvar,
    const float* __restrict__ Wo, const float* __restrict__ bo,
    const float* __restrict__ og, const float* __restrict__ ob,
    const float* __restrict__ om, const float* __restrict__ ovar,
    float* __restrict__ ws)
{
    const int idx = blockIdx.x * 256 + threadIdx.x;
    if (idx < 2048) {                       // WqT[c][i]
        const int c = idx >> 5, i = idx & 31;
        const float s = qg[i] * rsqrtf(qv[i] + 1e-5f);
        ws[OFF_WQT + idx] = Wq[i * 64 + c] * s;
    } else if (idx < 2080) {
        const int i = idx - 2048;
        const float s = qg[i] * rsqrtf(qv[i] + 1e-5f);
        ws[OFF_BQ + i] = bq[i] * s + qb[i] - qm[i] * s;
    } else if (idx < 4128) {                // WkT[c][i]
        const int t = idx - 2080;
        const int c = t >> 5, i = t & 31;
        const float s = kg[i] * rsqrtf(kvar[i] + 1e-5f);
        ws[OFF_WKT + t] = Wk[i * 64 + c] * s;
    } else if (idx < 4160) {
        const int i = idx - 4128;
        const float s = kg[i] * rsqrtf(kvar[i] + 1e-5f);
        ws[OFF_BK + i] = bk[i] * s + kb[i] - km[i] * s;
    } else if (idx < 8256) {                // WvT[c][o]
        const int t = idx - 4160;
        const int c = t >> 6, o = t & 63;
        const float s = vg[o] * rsqrtf(vvar[o] + 1e-5f);
        ws[OFF_WVT + t] = Wv[o * 64 + c] * s;
    } else if (idx < 8320) {
        const int o = idx - 8256;
        const float s = vg[o] * rsqrtf(vvar[o] + 1e-5f);
        ws[OFF_BV + o] = bv[o] * s + vb[o] - vm[o] * s;
    } else if (idx < 12416) {               // Wo'[c][j]
        const int t = idx - 8320;
        const int c = t >> 6, j = t & 63;
        const float s = og[c] * rsqrtf(ovar[c] + 1e-5f);
        ws[OFF_WO + t] = Wo[c * 64 + j] * s;
    } else if (idx < 12480) {
        const int c = idx - 12416;
        const float s = og[c] * rsqrtf(ovar[c] + 1e-5f);
        ws[OFF_BO + c] = bo[c] * s + ob[c] - om[c] * s;
    } else if (idx < 12480 + 32768) {       // zero F (must happen every launch)
        ws[OFF_F + (idx - 12480)] = 0.0f;
    }
}

// Pass A: 256 threads/block, each thread owns 1 pixel per chunk.
// Weights are wave-uniform -> read from global (scalar/K$ path), NOT LDS.
// LDS only stages 64 pixels of k/v at a time (4 rounds per 256-px chunk).
__global__ __launch_bounds__(256, 2) void k1_passA(const float* __restrict__ x,
                                                   const float* __restrict__ wsc,
                                                   float* __restrict__ f)
{
    __shared__ float Kl[64 * 36];   // 64 px staged, stride 36 floats
    __shared__ float Vl[64 * 68];   // 64 px staged, stride 68 floats

    const int tid = threadIdx.x;
    const int n = blockIdx.x / BPN_A;
    const int bslot = blockIdx.x % BPN_A;

    const int half = tid >> 7;          // s2-range half
    const int t7 = tid & 127;
    const int i0 = (t7 & 7) * 4;        // k-row group (8 groups x 4)
    const int j0 = (t7 >> 3) * 4;       // v-col group (16 groups x 4)
    const int grp = tid >> 6;           // staging round owner (wave id)
    const int lane = tid & 63;

    const float4* wk4 = (const float4*)(wsc + OFF_WKT);   // [64][8]
    const float4* wv4 = (const float4*)(wsc + OFF_WVT);   // [64][16]

    float facc[4][4];
#pragma unroll
    for (int a = 0; a < 4; a++)
#pragma unroll
        for (int b = 0; b < 4; b++) facc[a][b] = 0.0f;

    const float* xn = x + (size_t)n * CCH * HW;

    for (int chunk = bslot; chunk < HW / 256; chunk += BPN_A) {
        const int s = chunk * 256 + tid;
        float kk[32], vv[64];
#pragma unroll
        for (int i = 0; i < 32; i++) kk[i] = wsc[OFF_BK + i];
#pragma unroll
        for (int o = 0; o < 64; o++) vv[o] = wsc[OFF_BV + o];

#pragma unroll 4
        for (int c = 0; c < 64; c++) {
            const float xc = xn[(size_t)c * HW + s];
#pragma unroll
            for (int i4 = 0; i4 < 8; i4++) {
                const float4 w = wk4[c * 8 + i4];
                kk[i4 * 4 + 0] += w.x * xc;
                kk[i4 * 4 + 1] += w.y * xc;
                kk[i4 * 4 + 2] += w.z * xc;
                kk[i4 * 4 + 3] += w.w * xc;
            }
#pragma unroll
            for (int o4 = 0; o4 < 16; o4++) {
                const float4 w = wv4[c * 16 + o4];
                vv[o4 * 4 + 0] += w.x * xc;
                vv[o4 * 4 + 1] += w.y * xc;
                vv[o4 * 4 + 2] += w.z * xc;
                vv[o4 * 4 + 3] += w.w * xc;
            }
        }

        float ssum = 0.0f;
#pragma unroll
        for (int i = 0; i < 32; i++) ssum += kk[i] * kk[i];
        const float inv = 1.0f / fmaxf(sqrtf(ssum), 1e-12f);
#pragma unroll
        for (int i = 0; i < 32; i++) kk[i] *= inv;
#pragma unroll
        for (int o = 0; o < 64; o++) vv[o] = fmaxf(vv[o], 0.0f);

#pragma unroll 1
        for (int r = 0; r < 4; ++r) {
            if (grp == r) {
#pragma unroll
                for (int i4 = 0; i4 < 8; i4++)
                    *(float4*)&Kl[lane * 36 + i4 * 4] =
                        make_float4(kk[i4 * 4], kk[i4 * 4 + 1], kk[i4 * 4 + 2], kk[i4 * 4 + 3]);
#pragma unroll
                for (int o4 = 0; o4 < 16; o4++)
                    *(float4*)&Vl[lane * 68 + o4 * 4] =
                        make_float4(vv[o4 * 4], vv[o4 * 4 + 1], vv[o4 * 4 + 2], vv[o4 * 4 + 3]);
            }
            __syncthreads();
            const int sbase = half * 32;
#pragma unroll 2
            for (int s2 = 0; s2 < 32; ++s2) {
                const float4 k4 = *(const float4*)&Kl[(sbase + s2) * 36 + i0];
                const float4 v4 = *(const float4*)&Vl[(sbase + s2) * 68 + j0];
                const float ka[4] = {k4.x, k4.y, k4.z, k4.w};
                const float va[4] = {v4.x, v4.y, v4.z, v4.w};
#pragma unroll
                for (int a = 0; a < 4; a++)
#pragma unroll
                    for (int b = 0; b < 4; b++) facc[a][b] += ka[a] * va[b];
            }
            __syncthreads();
        }
    }

    // merge the two s2-halves via LDS, then one atomic set per slot
    if (half == 1) {
#pragma unroll
        for (int a = 0; a < 4; a++)
#pragma unroll
            for (int b = 0; b < 4; b++) Kl[t7 * 16 + a * 4 + b] = facc[a][b];
    }
    __syncthreads();
    if (half == 0) {
        float* fn = f + n * (QKC * CCH);
#pragma unroll
        for (int a = 0; a < 4; a++)
#pragma unroll
            for (int b = 0; b < 4; b++)
                atomicAdd(&fn[(i0 + a) * 64 + (j0 + b)],
                          facc[a][b] + Kl[t7 * 16 + a * 4 + b]);
    }
}

// MT[n][i][c] = sum_j Wo'[c][j] * F[n][i][j]
__global__ __launch_bounds__(256) void k2_M(const float* __restrict__ wsc,
                                            float* __restrict__ ws)
{
    const int idx = blockIdx.x * 256 + threadIdx.x;
    if (idx >= NBATCH * QKC * CCH) return;
    const int n = idx / (QKC * CCH);
    const int r = idx % (QKC * CCH);
    const int i = r >> 6, c = r & 63;
    const float* wo = wsc + OFF_WO + c * 64;
    const float* fr = wsc + OFF_F + n * 2048 + i * 64;
    float acc = 0.0f;
#pragma unroll
    for (int j = 0; j < 64; j++) acc += wo[j] * fr[j];
    ws[OFF_MT + idx] = acc;
}

// Pass B: zero LDS. Two streaming passes over x per pixel:
//   pass1: q = norm(WqT x + bq); oo = relu(MT^T q + bo)
//   pass2: oo += WvT x   ; store oo + bv
__global__ __launch_bounds__(256, 2) void k3_passB(const float* __restrict__ x,
                                                   const float* __restrict__ wsc,
                                                   float* __restrict__ out)
{
    const int tid = threadIdx.x;
    const int n = blockIdx.x / BPN_B;
    const int slot = blockIdx.x % BPN_B;

    const float4* wq4 = (const float4*)(wsc + OFF_WQT);          // [64][8]
    const float4* wv4 = (const float4*)(wsc + OFF_WVT);          // [64][16]
    const float4* mt4 = (const float4*)(wsc + OFF_MT + n * 2048); // [32][16]
    const float4* bo4 = (const float4*)(wsc + OFF_BO);
    const float4* bv4 = (const float4*)(wsc + OFF_BV);

    const float* xn = x + (size_t)n * CCH * HW;
    float* on = out + (size_t)n * CCH * HW;

    for (int it = 0; it < HW / (BPN_B * 256); it++) {
        const int s = slot * (HW / BPN_B) + it * 256 + tid;

        // ---- q ----
        float q[32];
#pragma unroll
        for (int i = 0; i < 32; i++) q[i] = wsc[OFF_BQ + i];
#pragma unroll 4
        for (int c = 0; c < 64; c++) {
            const float xc = xn[(size_t)c * HW + s];
#pragma unroll
            for (int i4 = 0; i4 < 8; i4++) {
                const float4 w = wq4[c * 8 + i4];
                q[i4 * 4 + 0] += w.x * xc;
                q[i4 * 4 + 1] += w.y * xc;
                q[i4 * 4 + 2] += w.z * xc;
                q[i4 * 4 + 3] += w.w * xc;
            }
        }
        float ssum = 0.0f;
#pragma unroll
        for (int i = 0; i < 32; i++) ssum += q[i] * q[i];
        const float inv = 1.0f / fmaxf(sqrtf(ssum), 1e-12f);
#pragma unroll
        for (int i = 0; i < 32; i++) q[i] *= inv;

        // ---- oo = MT^T q + bo ----
        float oo[64];
#pragma unroll
        for (int c4 = 0; c4 < 16; c4++) {
            const float4 b = bo4[c4];
            oo[c4 * 4 + 0] = b.x; oo[c4 * 4 + 1] = b.y;
            oo[c4 * 4 + 2] = b.z; oo[c4 * 4 + 3] = b.w;
        }
#pragma unroll 4
        for (int i = 0; i < 32; i++) {
            const float qi = q[i];
#pragma unroll
            for (int c4 = 0; c4 < 16; c4++) {
                const float4 m = mt4[i * 16 + c4];
                oo[c4 * 4 + 0] += m.x * qi;
                oo[c4 * 4 + 1] += m.y * qi;
                oo[c4 * 4 + 2] += m.z * qi;
                oo[c4 * 4 + 3] += m.w * qi;
            }
        }
#pragma unroll
        for (int c = 0; c < 64; c++) oo[c] = fmaxf(oo[c], 0.0f);

        // ---- oo += v0 (stream x again) ----
#pragma unroll 4
        for (int c = 0; c < 64; c++) {
            const float xc = xn[(size_t)c * HW + s];
#pragma unroll
            for (int o4 = 0; o4 < 16; o4++) {
                const float4 w = wv4[c * 16 + o4];
                oo[o4 * 4 + 0] += w.x * xc;
                oo[o4 * 4 + 1] += w.y * xc;
                oo[o4 * 4 + 2] += w.z * xc;
                oo[o4 * 4 + 3] += w.w * xc;
            }
        }

        // ---- store out = oo + bv ----
#pragma unroll
        for (int o4 = 0; o4 < 16; o4++) {
            const float4 b = bv4[o4];
            on[(size_t)(o4 * 4 + 0) * HW + s] = oo[o4 * 4 + 0] + b.x;
            on[(size_t)(o4 * 4 + 1) * HW + s] = oo[o4 * 4 + 1] + b.y;
            on[(size_t)(o4 * 4 + 2) * HW + s] = oo[o4 * 4 + 2] + b.z;
            on[(size_t)(o4 * 4 + 3) * HW + s] = oo[o4 * 4 + 3] + b.w;
        }
    }
}

extern "C" void kernel_launch(void* const* d_in, const int* in_sizes, int n_in,
                              void* d_out, int out_size, void* d_ws, size_t ws_size,
                              hipStream_t stream)
{
    const float* x    = (const float*)d_in[0];
    const float* Wq   = (const float*)d_in[1];
    const float* bq   = (const float*)d_in[2];
    const float* qg   = (const float*)d_in[3];
    const float* qb   = (const float*)d_in[4];
    const float* qm   = (const float*)d_in[5];
    const float* qv   = (const float*)d_in[6];
    const float* Wk   = (const float*)d_in[7];
    const float* bk   = (const float*)d_in[8];
    const float* kg   = (const float*)d_in[9];
    const float* kb   = (const float*)d_in[10];
    const float* km   = (const float*)d_in[11];
    const float* kvar = (const float*)d_in[12];
    const float* Wv   = (const float*)d_in[13];
    const float* bv   = (const float*)d_in[14];
    const float* vg   = (const float*)d_in[15];
    const float* vb   = (const float*)d_in[16];
    const float* vm   = (const float*)d_in[17];
    const float* vvar = (const float*)d_in[18];
    const float* Wo   = (const float*)d_in[19];
    const float* bo   = (const float*)d_in[20];
    const float* og   = (const float*)d_in[21];
    const float* ob   = (const float*)d_in[22];
    const float* om   = (const float*)d_in[23];
    const float* ovar = (const float*)d_in[24];

    float* ws  = (float*)d_ws;
    float* out = (float*)d_out;

    k0_fold<<<177, 256, 0, stream>>>(Wq, bq, qg, qb, qm, qv,
                                     Wk, bk, kg, kb, km, kvar,
                                     Wv, bv, vg, vb, vm, vvar,
                                     Wo, bo, og, ob, om, ovar, ws);

    k1_passA<<<NBATCH * BPN_A, 256, 0, stream>>>(x, (const float*)ws, ws + OFF_F);

    k2_M<<<128, 256, 0, stream>>>((const float*)ws, ws);

    k3_passB<<<NBATCH * BPN_B, 256, 0, stream>>>(x, (const float*)ws, out);
}